// Round 9
// baseline (321.297 us; speedup 1.0000x reference)
//
#include <hip/hip_runtime.h>
#include <hip/hip_bf16.h>
#include <math.h>

#define N_NODES 50000
#define N_EDGES 800000
#define RNPAD   50048   // per-replica counter stride (>= N_NODES, 16-aligned)
#define NREP    8       // one counter/bucket replica per XCD
#define CAPR    16      // bucket row per replica = 16 ushorts = 32B
#define MAX_OVF 8192    // exact-correctness overflow list (P ~ 1e-4 edges)

typedef __bf16 bf16x8 __attribute__((ext_vector_type(8)));
typedef float f32x4 __attribute__((ext_vector_type(4)));

// ---------------------------------------------------------------------------
// K1: prep. [0,1024): U[i]=(W1a-W1b)x_i+b1 ; V[j]=W1b x_j (wave/node).
//          [1024,1040): W2 -> bf16 (single-precision B; A stays hi/lo split).
// ---------------------------------------------------------------------------
#define UV_BLOCKS 1024
#define W2_BLOCKS 16
#define PREP_GRID (UV_BLOCKS + W2_BLOCKS)

__global__ __launch_bounds__(256) void prep_kernel(
    const float* __restrict__ x, const float* __restrict__ W1,
    const float* __restrict__ b1, const float* __restrict__ W2,
    float* __restrict__ U, float* __restrict__ V, __bf16* __restrict__ w2h)
{
    const int blk = blockIdx.x;
    if (blk < UV_BLOCKS) {
        const int lane = threadIdx.x & 63;
        const int wave = (int)((blk * 256 + threadIdx.x) >> 6);
        const int nwav = UV_BLOCKS * 4;

        float wa[64], wb[64];
#pragma unroll
        for (int k4 = 0; k4 < 16; ++k4) {
            float4 pa = *(const float4*)(W1 + lane * 128 + k4 * 4);
            float4 pb = *(const float4*)(W1 + lane * 128 + 64 + k4 * 4);
            wa[k4 * 4 + 0] = pa.x - pb.x;  wb[k4 * 4 + 0] = pb.x;
            wa[k4 * 4 + 1] = pa.y - pb.y;  wb[k4 * 4 + 1] = pb.y;
            wa[k4 * 4 + 2] = pa.z - pb.z;  wb[k4 * 4 + 2] = pb.z;
            wa[k4 * 4 + 3] = pa.w - pb.w;  wb[k4 * 4 + 3] = pb.w;
        }
        const float bias = b1[lane];

        for (int i = wave; i < N_NODES; i += nwav) {
            float xv = x[i * 64 + lane];
            float u = bias, v = 0.f;
#pragma unroll
            for (int k = 0; k < 64; ++k) {
                float xk = __int_as_float(
                    __builtin_amdgcn_readlane(__float_as_int(xv), k));
                u = fmaf(wa[k], xk, u);
                v = fmaf(wb[k], xk, v);
            }
            U[i * 64 + lane] = u;
            V[i * 64 + lane] = v;
        }
    } else {
        const int i = (blk - UV_BLOCKS) * 256 + threadIdx.x;
        if (i < 64 * 64) w2h[i] = (__bf16)W2[i];
    }
}

// ---------------------------------------------------------------------------
// K2: XCD-private bucket scatter. R8 post-mortem: padding didn't help because
// the cost is cross-XCD atomic LINE MIGRATION (~15 G line-txn/s, ~60 B
// writeback per RMW). Fix: 8 counter/bucket replicas; each block writes only
// the replica of the XCD it runs on (s_getreg HW_REG_XCC_ID, m09-verified).
// Correct under ANY block->XCD mapping (node kernel sums all replicas);
// with the real mapping, every counter/bucket line is single-XCD -> atomics
// stay in local L2, no migration. Poison-base: slot NREP*RNPAD untouched;
// deg_r = count - base. Overflow cursor at NREP*RNPAD+16 (separate line).
// ---------------------------------------------------------------------------
__global__ __launch_bounds__(256) void scatter_kernel(
    const int* __restrict__ ei, unsigned* __restrict__ uc,
    unsigned short* __restrict__ bk, int2* __restrict__ ovf)
{
    unsigned xcc = 0;
    asm volatile("s_getreg_b32 %0, hwreg(HW_REG_XCC_ID)" : "=s"(xcc));
    const int rep = (int)(xcc & 7u);
    unsigned* __restrict__ myc = uc + (size_t)rep * RNPAD;
    unsigned short* __restrict__ myb = bk + (size_t)rep * RNPAD * CAPR;
    const unsigned ub = uc[(size_t)NREP * RNPAD];

    const int tid = blockIdx.x * 256 + threadIdx.x;
    const int stride = gridDim.x * 256;
    for (int e = tid; e < N_EDGES; e += stride) {
        const int s = ei[e];
        const int d = ei[N_EDGES + e];
        unsigned pos = atomicAdd(&myc[d], 1u) - ub;
        if (pos < CAPR) {
            myb[d * CAPR + (int)pos] = (unsigned short)s;
        } else {
            unsigned o = atomicAdd(&uc[(size_t)NREP * RNPAD + 16], 1u) - ub;
            if (o < MAX_OVF) ovf[o] = make_int2(d, s);
        }
    }
}

// ---------------------------------------------------------------------------
// Tile compute: repack h=leaky(uf+v) fp32 -> A hi/lo bf16 frags; 4 MFMA per t
// (B = single bf16, loaded per-tile -> L1-resident); masked max over rows
// 4q+r < lim, shfl-reduce over q, fold into rm[4].
//   A: lane m+16q holds A[m][k], k=32s+8q+j   B: lane n+16q holds W2[n][k]
//   D: lane holds D[4q+r][lane&15]
// ---------------------------------------------------------------------------
__device__ __forceinline__ void tile_mfma_max(
    const float4* __restrict__ uf4, const float4* __restrict__ v4,
    const __bf16* __restrict__ w2h, int m, int q, int lim,
    float* __restrict__ rm)
{
    bf16x8 ahi[2], alo[2];
#pragma unroll
    for (int s = 0; s < 2; ++s) {
        const float4 a = uf4[2 * s], b = uf4[2 * s + 1];
        const float4 c = v4[2 * s],  d = v4[2 * s + 1];
        float hv[8] = {a.x + c.x, a.y + c.y, a.z + c.z, a.w + c.w,
                       b.x + d.x, b.y + d.y, b.z + d.z, b.w + d.w};
#pragma unroll
        for (int j = 0; j < 8; ++j) {
            float h = fmaxf(hv[j], 0.01f * hv[j]);   // LeakyReLU
            __bf16 hb = (__bf16)h;
            ahi[s][j] = hb;
            alo[s][j] = (__bf16)(h - (float)hb);     // residual
        }
    }
#pragma unroll
    for (int t = 0; t < 4; ++t) {
        const bf16x8 b0 = *(const bf16x8*)(w2h + (t * 16 + m) * 64 + q * 8);
        const bf16x8 b1 = *(const bf16x8*)(w2h + (t * 16 + m) * 64 + 32 + q * 8);
        f32x4 acc = {0.f, 0.f, 0.f, 0.f};
        acc = __builtin_amdgcn_mfma_f32_16x16x32_bf16(ahi[0], b0, acc, 0, 0, 0);
        acc = __builtin_amdgcn_mfma_f32_16x16x32_bf16(alo[0], b0, acc, 0, 0, 0);
        acc = __builtin_amdgcn_mfma_f32_16x16x32_bf16(ahi[1], b1, acc, 0, 0, 0);
        acc = __builtin_amdgcn_mfma_f32_16x16x32_bf16(alo[1], b1, acc, 0, 0, 0);
        float v = -INFINITY;
#pragma unroll
        for (int r = 0; r < 4; ++r)
            if (4 * q + r < lim) v = fmaxf(v, acc[r]);   // mask garbage rows
        v = fmaxf(v, __shfl_xor(v, 16, 64));
        v = fmaxf(v, __shfl_xor(v, 32, 64));
        rm[t] = fmaxf(rm[t], v);
    }
}

__device__ __forceinline__ void load_v4(const float* __restrict__ V,
                                        unsigned si, int q, float4* v4)
{
    const float* b0 = V + (size_t)si * 64 + q * 8;
    v4[0] = ((const float4*)b0)[0];
    v4[1] = ((const float4*)b0)[1];
    const float* b1 = b0 + 32;
    v4[2] = ((const float4*)b1)[0];
    v4[3] = ((const float4*)b1)[1];
}

// slot g of node n's concatenated (8-replica) list -> bucket element index
__device__ __forceinline__ int bkt_index(int g, int n, const int* __restrict__ pre)
{
    int rsel = 0;
#pragma unroll
    for (int r = 1; r < 8; ++r)
        if (g >= pre[r]) rsel = r;                 // last r with pre[r] <= g
    int slot = g - pre[rsel];
    if (slot < 0) slot = 0;
    if (slot > CAPR - 1) slot = CAPR - 1;          // paranoia clamp
    return (rsel * RNPAD + n) * CAPR + slot;
}

// ---------------------------------------------------------------------------
// K3: wave per node, 3-deep software pipeline (bucket addrs now depend on
// counts -> prefix): iter for node n issues cnt(n+3s), prefix+bkt(n+2s),
// V/U(n+1s), computes n. All loads poison-safe (si clamp, -INF row mask),
// so nothing waits on the scatter ordering beyond real data deps.
// 1024 blocks @ (256,4): all resident.
// ---------------------------------------------------------------------------
__global__ __launch_bounds__(256, 4) void node_kernel(
    const unsigned* __restrict__ uc, const unsigned short* __restrict__ bk,
    const int2* __restrict__ ovf,
    const float* __restrict__ U, const float* __restrict__ V,
    const __bf16* __restrict__ w2h, const float* __restrict__ b2,
    float* __restrict__ out)
{
    const int lane = threadIdx.x & 63;
    const int m    = lane & 15;
    const int q    = lane >> 4;
    const int wave = (int)((blockIdx.x * blockDim.x + threadIdx.x) >> 6);
    const int nwav = (int)((gridDim.x * blockDim.x) >> 6);
    const int last = N_NODES - 1;

    const float b2v = b2[lane];
    const unsigned ub = uc[(size_t)NREP * RNPAD];

#define LOAD_CNT8(n, c8)                                                     \
    {  _Pragma("unroll")                                                     \
       for (int r = 0; r < 8; ++r) (c8)[r] = uc[r * RNPAD + (n)]; }

#define MK_PREFIX(c8, pre, flag)                                             \
    {  int acc_ = 0; (flag) = false;                                         \
       _Pragma("unroll")                                                     \
       for (int r = 0; r < 8; ++r) {                                         \
           (pre)[r] = acc_;                                                  \
           unsigned d_ = (c8)[r] - ub;                                       \
           if (d_ > CAPR) { (flag) = true; d_ = CAPR; }                      \
           acc_ += (int)d_;                                                  \
       }                                                                     \
       (pre)[8] = acc_; }

#define LOAD_UF(n, uf)                                                       \
    {  const float* ub0_ = U + (size_t)(n) * 64 + q * 8;                     \
       (uf)[0] = ((const float4*)ub0_)[0];                                   \
       (uf)[1] = ((const float4*)ub0_)[1];                                   \
       (uf)[2] = ((const float4*)(ub0_ + 32))[0];                            \
       (uf)[3] = ((const float4*)(ub0_ + 32))[1]; }

    // ---- prologue ----
    const int nA0 = wave;                       // wave < 4096 < N_NODES
    int nB0 = nA0 + nwav;     if (nB0 > last) nB0 = last;
    int nC0 = nA0 + 2 * nwav; if (nC0 > last) nC0 = last;

    unsigned cC8[8];
    int preA[9], preB[9];
    bool ovA, ovB;
    {
        unsigned cA8[8], cB8[8];
        LOAD_CNT8(nA0, cA8); LOAD_CNT8(nB0, cB8); LOAD_CNT8(nC0, cC8);
        MK_PREFIX(cA8, preA, ovA); MK_PREFIX(cB8, preB, ovB);
    }

    int gA = m; if (gA > preA[8] - 1) gA = (preA[8] > 0) ? preA[8] - 1 : 0;
    int bktA = bk[bkt_index(gA, nA0, preA)];
    int gB = m; if (gB > preB[8] - 1) gB = (preB[8] > 0) ? preB[8] - 1 : 0;
    int bktB = bk[bkt_index(gB, nB0, preB)];

    float4 vA[4];
    {
        unsigned si = (unsigned)bktA;
        if (si >= N_NODES) si = N_NODES - 1;    // poison-safe clamp
        load_v4(V, si, q, vA);
    }
    float4 ufA[4], ufB[4];
    LOAD_UF(nA0, ufA);
    LOAD_UF(nB0, ufB);

    for (int n = nA0; n < N_NODES; n += nwav) {
        int nC = n + 2 * nwav; if (nC > last) nC = last;
        int nD = n + 3 * nwav; if (nD > last) nD = last;

        // (1) issue cnt(D)
        unsigned cD8[8];
        LOAD_CNT8(nD, cD8);

        // (2) prefix(C) from arrived cC8; issue bkt(C)
        int preC[9]; bool ovC;
        MK_PREFIX(cC8, preC, ovC);
        int gC = m; if (gC > preC[8] - 1) gC = (preC[8] > 0) ? preC[8] - 1 : 0;
        int bktC = bk[bkt_index(gC, nC, preC)];

        // (3) issue V(B) from arrived bktB
        unsigned siB = (unsigned)bktB;
        if (siB >= N_NODES) siB = N_NODES - 1;
        float4 vB[4];
        load_v4(V, siB, q, vB);

        // (4) compute node A = n
        const int deg = preA[8];
        float rm[4] = {-INFINITY, -INFINITY, -INFINITY, -INFINITY};
        const int lim0 = (deg < 16) ? deg : 16;
        tile_mfma_max(ufA, vA, w2h, m, q, lim0, rm);      // tile 0 (pre-armed)

        for (int base = 16; base < deg; base += 16) {     // tiles 1.. (deg>16)
            int g = base + m; if (g > deg - 1) g = deg - 1;   // dup-pad
            unsigned si = (unsigned)bk[bkt_index(g, n, preA)];
            if (si >= N_NODES) si = N_NODES - 1;
            float4 v4[4];
            load_v4(V, si, q, v4);
            int lim = deg - base; if (lim > 16) lim = 16;
            tile_mfma_max(ufA, v4, w2h, m, q, lim, rm);
        }

        if (ovA) {   // exact fallback: some replica overflowed -> scan list
            unsigned nou = uc[(size_t)NREP * RNPAD + 16] - ub;
            int no = (nou < MAX_OVF) ? (int)nou : MAX_OVF;
            for (int o = 0; o < no; ++o) {
                const int2 ds = ovf[o];
                if (ds.x != n) continue;
                unsigned si = (unsigned)ds.y;
                if (si >= N_NODES) si = N_NODES - 1;
                float4 v4[4];
                load_v4(V, si, q, v4);
                tile_mfma_max(ufA, v4, w2h, m, q, 16, rm);
            }
        }

        const float sel = (q == 0) ? rm[0] : (q == 1) ? rm[1]
                        : (q == 2) ? rm[2] : rm[3];       // col == lane
        out[(size_t)n * 64 + lane] = (deg != 0) ? tanhf(sel + b2v) : 0.f;

        // (5) rotate pipeline state; issue U(next B == current C)
#pragma unroll
        for (int i = 0; i < 9; ++i) { preA[i] = preB[i]; preB[i] = preC[i]; }
        ovA = ovB; ovB = ovC;
        bktB = bktC;
#pragma unroll
        for (int i = 0; i < 4; ++i) { vA[i] = vB[i]; ufA[i] = ufB[i]; }
#pragma unroll
        for (int r = 0; r < 8; ++r) cC8[r] = cD8[r];
        LOAD_UF(nC, ufB);
    }
#undef LOAD_CNT8
#undef MK_PREFIX
#undef LOAD_UF
}

// ---------------------------------------------------------------------------
extern "C" void kernel_launch(void* const* d_in, const int* in_sizes, int n_in,
                              void* d_out, int out_size, void* d_ws, size_t ws_size,
                              hipStream_t stream)
{
    const float* x  = (const float*)d_in[0];
    const int*   ei = (const int*)d_in[1];
    const float* W1 = (const float*)d_in[2];
    const float* b1 = (const float*)d_in[3];
    const float* W2 = (const float*)d_in[4];
    const float* b2 = (const float*)d_in[5];
    float* out = (float*)d_out;

    char* p = (char*)d_ws;
    float* U = (float*)p;                  p += (size_t)N_NODES * 64 * 4;
    float* V = (float*)p;                  p += (size_t)N_NODES * 64 * 4;
    __bf16* w2h = (__bf16*)p;              p += 64 * 64 * 2;
    unsigned* uc = (unsigned*)p;           p += ((size_t)NREP * RNPAD + 32) * 4;
    int2* ovf = (int2*)p;                  p += (size_t)MAX_OVF * 8;
    unsigned short* bk = (unsigned short*)p;
    p += (size_t)NREP * RNPAD * CAPR * 2;

    prep_kernel<<<PREP_GRID, 256, 0, stream>>>(x, W1, b1, W2, U, V, w2h);
    scatter_kernel<<<2048, 256, 0, stream>>>(ei, uc, bk, ovf);
    node_kernel<<<1024, 256, 0, stream>>>(uc, bk, ovf, U, V, w2h, b2, out);
}

// Round 10
// 264.209 us; speedup vs baseline: 1.2161x; 1.2161x over previous
//
#include <hip/hip_runtime.h>
#include <hip/hip_bf16.h>
#include <math.h>

#define N_NODES 50000
#define N_EDGES 800000
#define RNPAD   50048   // per-replica counter stride (>= N_NODES, 16-aligned)
#define NREP    8       // one counter/bucket replica per XCD
#define CAPR    16      // bucket row per replica = 16 ushorts = 32B
#define MAX_OVF 8192    // exact-correctness overflow list

typedef __bf16 bf16x8 __attribute__((ext_vector_type(8)));
typedef float f32x4 __attribute__((ext_vector_type(4)));

// ---------------------------------------------------------------------------
// K1: prep. [0,1024): U[i]=(W1a-W1b)x_i+b1 ; V[j]=W1b x_j (wave/node).
//          [1024,1040): W2 -> bf16 (single-precision B; A stays hi/lo split).
// ---------------------------------------------------------------------------
#define UV_BLOCKS 1024
#define W2_BLOCKS 16
#define PREP_GRID (UV_BLOCKS + W2_BLOCKS)

__global__ __launch_bounds__(256) void prep_kernel(
    const float* __restrict__ x, const float* __restrict__ W1,
    const float* __restrict__ b1, const float* __restrict__ W2,
    float* __restrict__ U, float* __restrict__ V, __bf16* __restrict__ w2h)
{
    const int blk = blockIdx.x;
    if (blk < UV_BLOCKS) {
        const int lane = threadIdx.x & 63;
        const int wave = (int)((blk * 256 + threadIdx.x) >> 6);
        const int nwav = UV_BLOCKS * 4;

        float wa[64], wb[64];
#pragma unroll
        for (int k4 = 0; k4 < 16; ++k4) {
            float4 pa = *(const float4*)(W1 + lane * 128 + k4 * 4);
            float4 pb = *(const float4*)(W1 + lane * 128 + 64 + k4 * 4);
            wa[k4 * 4 + 0] = pa.x - pb.x;  wb[k4 * 4 + 0] = pb.x;
            wa[k4 * 4 + 1] = pa.y - pb.y;  wb[k4 * 4 + 1] = pb.y;
            wa[k4 * 4 + 2] = pa.z - pb.z;  wb[k4 * 4 + 2] = pb.z;
            wa[k4 * 4 + 3] = pa.w - pb.w;  wb[k4 * 4 + 3] = pb.w;
        }
        const float bias = b1[lane];

        for (int i = wave; i < N_NODES; i += nwav) {
            float xv = x[i * 64 + lane];
            float u = bias, v = 0.f;
#pragma unroll
            for (int k = 0; k < 64; ++k) {
                float xk = __int_as_float(
                    __builtin_amdgcn_readlane(__float_as_int(xv), k));
                u = fmaf(wa[k], xk, u);
                v = fmaf(wb[k], xk, v);
            }
            U[i * 64 + lane] = u;
            V[i * 64 + lane] = v;
        }
    } else {
        const int i = (blk - UV_BLOCKS) * 256 + threadIdx.x;
        if (i < 64 * 64) w2h[i] = (__bf16)W2[i];
    }
}

// ---------------------------------------------------------------------------
// K2: XCD-private bucket scatter (unchanged from R9; finally measurable this
// round). Each block writes only the replica of the XCD it runs on -> every
// counter/bucket line is single-XCD -> atomics stay in local L2, no cross-XCD
// line migration. Correct under ANY block->XCD mapping (node merges all 8).
// Poison-base: slot NREP*RNPAD untouched; overflow cursor at +16.
// ---------------------------------------------------------------------------
__global__ __launch_bounds__(256) void scatter_kernel(
    const int* __restrict__ ei, unsigned* __restrict__ uc,
    unsigned short* __restrict__ bk, int2* __restrict__ ovf)
{
    unsigned xcc = 0;
    asm volatile("s_getreg_b32 %0, hwreg(HW_REG_XCC_ID)" : "=s"(xcc));
    const int rep = (int)(xcc & 7u);
    unsigned* __restrict__ myc = uc + (size_t)rep * RNPAD;
    unsigned short* __restrict__ myb = bk + (size_t)rep * RNPAD * CAPR;
    const unsigned ub = uc[(size_t)NREP * RNPAD];

    const int tid = blockIdx.x * 256 + threadIdx.x;
    const int stride = gridDim.x * 256;
    for (int e = tid; e < N_EDGES; e += stride) {
        const int s = ei[e];
        const int d = ei[N_EDGES + e];
        unsigned pos = atomicAdd(&myc[d], 1u) - ub;
        if (pos < CAPR) {
            myb[d * CAPR + (int)pos] = (unsigned short)s;
        } else {
            unsigned o = atomicAdd(&uc[(size_t)NREP * RNPAD + 16], 1u) - ub;
            if (o < MAX_OVF) ovf[o] = make_int2(d, s);
        }
    }
}

// ---------------------------------------------------------------------------
// Tile compute (unchanged): repack h=leaky(uf+v) -> A hi/lo bf16; 4 MFMA per
// t (B single bf16, per-tile L1 loads); masked max, shfl-reduce over q.
// ---------------------------------------------------------------------------
__device__ __forceinline__ void tile_mfma_max(
    const float4* __restrict__ uf4, const float4* __restrict__ v4,
    const __bf16* __restrict__ w2h, int m, int q, int lim,
    float* __restrict__ rm)
{
    bf16x8 ahi[2], alo[2];
#pragma unroll
    for (int s = 0; s < 2; ++s) {
        const float4 a = uf4[2 * s], b = uf4[2 * s + 1];
        const float4 c = v4[2 * s],  d = v4[2 * s + 1];
        float hv[8] = {a.x + c.x, a.y + c.y, a.z + c.z, a.w + c.w,
                       b.x + d.x, b.y + d.y, b.z + d.z, b.w + d.w};
#pragma unroll
        for (int j = 0; j < 8; ++j) {
            float h = fmaxf(hv[j], 0.01f * hv[j]);   // LeakyReLU
            __bf16 hb = (__bf16)h;
            ahi[s][j] = hb;
            alo[s][j] = (__bf16)(h - (float)hb);     // residual
        }
    }
#pragma unroll
    for (int t = 0; t < 4; ++t) {
        const bf16x8 b0 = *(const bf16x8*)(w2h + (t * 16 + m) * 64 + q * 8);
        const bf16x8 b1 = *(const bf16x8*)(w2h + (t * 16 + m) * 64 + 32 + q * 8);
        f32x4 acc = {0.f, 0.f, 0.f, 0.f};
        acc = __builtin_amdgcn_mfma_f32_16x16x32_bf16(ahi[0], b0, acc, 0, 0, 0);
        acc = __builtin_amdgcn_mfma_f32_16x16x32_bf16(alo[0], b0, acc, 0, 0, 0);
        acc = __builtin_amdgcn_mfma_f32_16x16x32_bf16(ahi[1], b1, acc, 0, 0, 0);
        acc = __builtin_amdgcn_mfma_f32_16x16x32_bf16(alo[1], b1, acc, 0, 0, 0);
        float v = -INFINITY;
#pragma unroll
        for (int r = 0; r < 4; ++r)
            if (4 * q + r < lim) v = fmaxf(v, acc[r]);   // mask garbage rows
        v = fmaxf(v, __shfl_xor(v, 16, 64));
        v = fmaxf(v, __shfl_xor(v, 32, 64));
        rm[t] = fmaxf(rm[t], v);
    }
}

__device__ __forceinline__ void load_v4(const float* __restrict__ V,
                                        unsigned si, int q, float4* v4)
{
    const float* b0 = V + (size_t)si * 64 + q * 8;
    v4[0] = ((const float4*)b0)[0];
    v4[1] = ((const float4*)b0)[1];
    const float* b1 = b0 + 32;
    v4[2] = ((const float4*)b1)[0];
    v4[3] = ((const float4*)b1)[1];
}

// Lane-parallel replica merge (R9 spill fix: no per-thread arrays).
// cntv: lane r<8 holds replica r's raw counter for the node.
// Returns inclusive prefix (lanes 0..7 valid); ov set if any replica >CAPR.
__device__ __forceinline__ int make_prefix(unsigned cntv, unsigned ub,
                                           int lane, bool& ov)
{
    unsigned degr = cntv - ub;
    if (lane >= 8) degr = 0;
    ov = (__ballot(degr > CAPR) != 0ULL);
    if (degr > CAPR) degr = CAPR;
    int incl = (int)degr;
    int t = __shfl_up(incl, 1, 64); if (lane >= 1) incl += t;
    t = __shfl_up(incl, 2, 64);     if (lane >= 2) incl += t;
    t = __shfl_up(incl, 4, 64);     if (lane >= 4) incl += t;
    return incl;            // lanes 8..63 garbage — only 0..7 read via shfl
}

// slot g of node n's concatenated 8-replica list -> bucket element index.
// incl = inclusive prefix in lanes 0..7 (7 shfl broadcasts, ~20 VALU).
__device__ __forceinline__ int merge_bkt_idx(int incl, int g, int n)
{
    int rsel = 0, pbase = 0;
#pragma unroll
    for (int r = 1; r < 8; ++r) {
        int pr = __shfl(incl, r - 1, 64);     // exclusive prefix of replica r
        if (g >= pr) { rsel = r; pbase = pr; }
    }
    int slot = g - pbase;
    if (slot < 0) slot = 0;
    if (slot > CAPR - 1) slot = CAPR - 1;
    return (rsel * RNPAD + n) * CAPR + slot;
}

// ---------------------------------------------------------------------------
// K3: wave per node, 3-deep pipeline with LANE-PARALLEL state (1 VGPR per
// count/prefix stage vs R9's spilled arrays): iter n issues cnt(n+3s),
// prefix+bkt(n+2s), V(n+1s), computes n. Poison-safe throughout.
// 1024 blocks @ (256,4): all resident.
// ---------------------------------------------------------------------------
__global__ __launch_bounds__(256, 4) void node_kernel(
    const unsigned* __restrict__ uc, const unsigned short* __restrict__ bk,
    const int2* __restrict__ ovf,
    const float* __restrict__ U, const float* __restrict__ V,
    const __bf16* __restrict__ w2h, const float* __restrict__ b2,
    float* __restrict__ out)
{
    const int lane = threadIdx.x & 63;
    const int m    = lane & 15;
    const int q    = lane >> 4;
    const int wave = (int)((blockIdx.x * blockDim.x + threadIdx.x) >> 6);
    const int nwav = (int)((gridDim.x * blockDim.x) >> 6);
    const int last = N_NODES - 1;

    const float b2v = b2[lane];
    const unsigned ub = uc[(size_t)NREP * RNPAD];

#define ISSUE_CNT(n) ((lane < 8) ? uc[lane * RNPAD + (n)] : 0u)
#define LOAD_UF(n, uf)                                                       \
    {  const float* ub0_ = U + (size_t)(n) * 64 + q * 8;                     \
       (uf)[0] = ((const float4*)ub0_)[0];                                   \
       (uf)[1] = ((const float4*)ub0_)[1];                                   \
       (uf)[2] = ((const float4*)(ub0_ + 32))[0];                            \
       (uf)[3] = ((const float4*)(ub0_ + 32))[1]; }

    // ---- prologue: A fully armed; B through bkt; C count in flight ----
    const int nA0 = wave;                        // wave < 4096 < N_NODES
    int nB0 = nA0 + nwav;     if (nB0 > last) nB0 = last;
    int nC0 = nA0 + 2 * nwav; if (nC0 > last) nC0 = last;

    unsigned cntA = ISSUE_CNT(nA0);
    unsigned cntB = ISSUE_CNT(nB0);
    unsigned cntC = ISSUE_CNT(nC0);             // consumed at iter 0

    bool ovA, ovB;
    int inclA = make_prefix(cntA, ub, lane, ovA);
    int inclB = make_prefix(cntB, ub, lane, ovB);

    int degA0 = __shfl(inclA, 7, 64);
    int gA = m; if (gA > degA0 - 1) gA = (degA0 > 0) ? degA0 - 1 : 0;
    int bktA = bk[merge_bkt_idx(inclA, gA, nA0)];
    int degB0 = __shfl(inclB, 7, 64);
    int gB = m; if (gB > degB0 - 1) gB = (degB0 > 0) ? degB0 - 1 : 0;
    int bktB = bk[merge_bkt_idx(inclB, gB, nB0)];

    float4 vA[4];
    {
        unsigned si = (unsigned)bktA;
        if (si >= N_NODES) si = N_NODES - 1;     // poison-safe clamp
        load_v4(V, si, q, vA);
    }
    float4 ufA[4], ufB[4];
    LOAD_UF(nA0, ufA);
    LOAD_UF(nB0, ufB);

    for (int n = nA0; n < N_NODES; n += nwav) {
        int nC = n + 2 * nwav; if (nC > last) nC = last;
        int nD = n + 3 * nwav; if (nD > last) nD = last;

        // (1) issue cnt(D)
        unsigned cntD = ISSUE_CNT(nD);

        // (2) prefix(C) from arrived cntC; issue bkt(C)
        bool ovC;
        int inclC = make_prefix(cntC, ub, lane, ovC);
        int degC = __shfl(inclC, 7, 64);
        int gC = m; if (gC > degC - 1) gC = (degC > 0) ? degC - 1 : 0;
        int bktC = bk[merge_bkt_idx(inclC, gC, nC)];

        // (3) issue V(B) from arrived bktB
        unsigned siB = (unsigned)bktB;
        if (siB >= N_NODES) siB = N_NODES - 1;
        float4 vB[4];
        load_v4(V, siB, q, vB);

        // (4) compute node A = n
        const int deg = __shfl(inclA, 7, 64);
        float rm[4] = {-INFINITY, -INFINITY, -INFINITY, -INFINITY};
        const int lim0 = (deg < 16) ? deg : 16;
        tile_mfma_max(ufA, vA, w2h, m, q, lim0, rm);     // tile 0 (pre-armed)

        for (int base = 16; base < deg; base += 16) {    // tiles 1.. (deg>16)
            int g = base + m; if (g > deg - 1) g = deg - 1;    // dup-pad
            unsigned si = (unsigned)bk[merge_bkt_idx(inclA, g, n)];
            if (si >= N_NODES) si = N_NODES - 1;
            float4 v4[4];
            load_v4(V, si, q, v4);
            int lim = deg - base; if (lim > 16) lim = 16;
            tile_mfma_max(ufA, v4, w2h, m, q, lim, rm);
        }

        if (ovA) {   // exact fallback: some replica overflowed -> scan list
            unsigned nou = uc[(size_t)NREP * RNPAD + 16] - ub;
            int no = (nou < MAX_OVF) ? (int)nou : MAX_OVF;
            for (int o = 0; o < no; ++o) {
                const int2 ds = ovf[o];
                if (ds.x != n) continue;
                unsigned si = (unsigned)ds.y;
                if (si >= N_NODES) si = N_NODES - 1;
                float4 v4[4];
                load_v4(V, si, q, v4);
                tile_mfma_max(ufA, v4, w2h, m, q, 16, rm);
            }
        }

        const float sel = (q == 0) ? rm[0] : (q == 1) ? rm[1]
                        : (q == 2) ? rm[2] : rm[3];      // col == lane
        out[(size_t)n * 64 + lane] = (deg != 0) ? tanhf(sel + b2v) : 0.f;

        // (5) rotate lane-parallel pipeline state; load U(next B == nC)
        inclA = inclB; inclB = inclC;
        ovA = ovB;     ovB = ovC;
        bktB = bktC;
        cntC = cntD;
#pragma unroll
        for (int i = 0; i < 4; ++i) { vA[i] = vB[i]; ufA[i] = ufB[i]; }
        LOAD_UF(nC, ufB);
    }
#undef ISSUE_CNT
#undef LOAD_UF
}

// ---------------------------------------------------------------------------
extern "C" void kernel_launch(void* const* d_in, const int* in_sizes, int n_in,
                              void* d_out, int out_size, void* d_ws, size_t ws_size,
                              hipStream_t stream)
{
    const float* x  = (const float*)d_in[0];
    const int*   ei = (const int*)d_in[1];
    const float* W1 = (const float*)d_in[2];
    const float* b1 = (const float*)d_in[3];
    const float* W2 = (const float*)d_in[4];
    const float* b2 = (const float*)d_in[5];
    float* out = (float*)d_out;

    char* p = (char*)d_ws;
    float* U = (float*)p;                  p += (size_t)N_NODES * 64 * 4;
    float* V = (float*)p;                  p += (size_t)N_NODES * 64 * 4;
    __bf16* w2h = (__bf16*)p;              p += 64 * 64 * 2;
    unsigned* uc = (unsigned*)p;           p += ((size_t)NREP * RNPAD + 32) * 4;
    int2* ovf = (int2*)p;                  p += (size_t)MAX_OVF * 8;
    unsigned short* bk = (unsigned short*)p;
    p += (size_t)NREP * RNPAD * CAPR * 2;

    prep_kernel<<<PREP_GRID, 256, 0, stream>>>(x, W1, b1, W2, U, V, w2h);
    scatter_kernel<<<2048, 256, 0, stream>>>(ei, uc, bk, ovf);
    node_kernel<<<1024, 256, 0, stream>>>(uc, bk, ovf, U, V, w2h, b2, out);
}

// Round 11
// 236.793 us; speedup vs baseline: 1.3569x; 1.1158x over previous
//
#include <hip/hip_runtime.h>
#include <hip/hip_bf16.h>
#include <math.h>

#define N_NODES 50000
#define N_EDGES 800000
#define RNPAD   50048   // per-replica counter stride (>= N_NODES, 16-aligned)
#define NREP    8       // one counter/bucket replica per XCD
#define CAPR    16      // bucket row per replica = 16 ushorts = 32B
#define MAX_OVF 8192    // exact-correctness overflow list (per-replica >CAPR)
#define MCAP    64      // merged-list LDS cap; P(merged deg>64) ~ 1e-18

typedef __bf16 bf16x8 __attribute__((ext_vector_type(8)));
typedef float f32x4 __attribute__((ext_vector_type(4)));

// ---------------------------------------------------------------------------
// K1: prep. [0,1024): U[i]=(W1a-W1b)x_i+b1 ; V[j]=W1b x_j (wave/node).
//          [1024,1040): W2 -> bf16 (single-precision B; A stays hi/lo split).
// ---------------------------------------------------------------------------
#define UV_BLOCKS 1024
#define W2_BLOCKS 16
#define PREP_GRID (UV_BLOCKS + W2_BLOCKS)

__global__ __launch_bounds__(256) void prep_kernel(
    const float* __restrict__ x, const float* __restrict__ W1,
    const float* __restrict__ b1, const float* __restrict__ W2,
    float* __restrict__ U, float* __restrict__ V, __bf16* __restrict__ w2h)
{
    const int blk = blockIdx.x;
    if (blk < UV_BLOCKS) {
        const int lane = threadIdx.x & 63;
        const int wave = (int)((blk * 256 + threadIdx.x) >> 6);
        const int nwav = UV_BLOCKS * 4;

        float wa[64], wb[64];
#pragma unroll
        for (int k4 = 0; k4 < 16; ++k4) {
            float4 pa = *(const float4*)(W1 + lane * 128 + k4 * 4);
            float4 pb = *(const float4*)(W1 + lane * 128 + 64 + k4 * 4);
            wa[k4 * 4 + 0] = pa.x - pb.x;  wb[k4 * 4 + 0] = pb.x;
            wa[k4 * 4 + 1] = pa.y - pb.y;  wb[k4 * 4 + 1] = pb.y;
            wa[k4 * 4 + 2] = pa.z - pb.z;  wb[k4 * 4 + 2] = pb.z;
            wa[k4 * 4 + 3] = pa.w - pb.w;  wb[k4 * 4 + 3] = pb.w;
        }
        const float bias = b1[lane];

        for (int i = wave; i < N_NODES; i += nwav) {
            float xv = x[i * 64 + lane];
            float u = bias, v = 0.f;
#pragma unroll
            for (int k = 0; k < 64; ++k) {
                float xk = __int_as_float(
                    __builtin_amdgcn_readlane(__float_as_int(xv), k));
                u = fmaf(wa[k], xk, u);
                v = fmaf(wb[k], xk, v);
            }
            U[i * 64 + lane] = u;
            V[i * 64 + lane] = v;
        }
    } else {
        const int i = (blk - UV_BLOCKS) * 256 + threadIdx.x;
        if (i < 64 * 64) w2h[i] = (__bf16)W2[i];
    }
}

// ---------------------------------------------------------------------------
// K2: XCD-private bucket scatter (unchanged). Each block writes only the
// replica of the XCD it runs on (s_getreg HW_REG_XCC_ID) -> counter/bucket
// lines are single-XCD -> atomics stay in local L2, no cross-XCD migration.
// Correct under ANY block->XCD mapping (node kernel merges all 8 replicas).
// Poison-base: slot NREP*RNPAD untouched; overflow cursor at +16.
// ---------------------------------------------------------------------------
__global__ __launch_bounds__(256) void scatter_kernel(
    const int* __restrict__ ei, unsigned* __restrict__ uc,
    unsigned short* __restrict__ bk, int2* __restrict__ ovf)
{
    unsigned xcc = 0;
    asm volatile("s_getreg_b32 %0, hwreg(HW_REG_XCC_ID)" : "=s"(xcc));
    const int rep = (int)(xcc & 7u);
    unsigned* __restrict__ myc = uc + (size_t)rep * RNPAD;
    unsigned short* __restrict__ myb = bk + (size_t)rep * RNPAD * CAPR;
    const unsigned ub = uc[(size_t)NREP * RNPAD];

    const int tid = blockIdx.x * 256 + threadIdx.x;
    const int stride = gridDim.x * 256;
    for (int e = tid; e < N_EDGES; e += stride) {
        const int s = ei[e];
        const int d = ei[N_EDGES + e];
        unsigned pos = atomicAdd(&myc[d], 1u) - ub;
        if (pos < CAPR) {
            myb[d * CAPR + (int)pos] = (unsigned short)s;
        } else {
            unsigned o = atomicAdd(&uc[(size_t)NREP * RNPAD + 16], 1u) - ub;
            if (o < MAX_OVF) ovf[o] = make_int2(d, s);
        }
    }
}

// ---------------------------------------------------------------------------
// Tile compute (unchanged): repack h=leaky(uf+v) -> A hi/lo bf16; 4 MFMA per
// t (B single bf16, per-tile L1 loads); masked max, shfl-reduce over q.
// ---------------------------------------------------------------------------
__device__ __forceinline__ void tile_mfma_max(
    const float4* __restrict__ uf4, const float4* __restrict__ v4,
    const __bf16* __restrict__ w2h, int m, int q, int lim,
    float* __restrict__ rm)
{
    bf16x8 ahi[2], alo[2];
#pragma unroll
    for (int s = 0; s < 2; ++s) {
        const float4 a = uf4[2 * s], b = uf4[2 * s + 1];
        const float4 c = v4[2 * s],  d = v4[2 * s + 1];
        float hv[8] = {a.x + c.x, a.y + c.y, a.z + c.z, a.w + c.w,
                       b.x + d.x, b.y + d.y, b.z + d.z, b.w + d.w};
#pragma unroll
        for (int j = 0; j < 8; ++j) {
            float h = fmaxf(hv[j], 0.01f * hv[j]);   // LeakyReLU
            __bf16 hb = (__bf16)h;
            ahi[s][j] = hb;
            alo[s][j] = (__bf16)(h - (float)hb);     // residual
        }
    }
#pragma unroll
    for (int t = 0; t < 4; ++t) {
        const bf16x8 b0 = *(const bf16x8*)(w2h + (t * 16 + m) * 64 + q * 8);
        const bf16x8 b1 = *(const bf16x8*)(w2h + (t * 16 + m) * 64 + 32 + q * 8);
        f32x4 acc = {0.f, 0.f, 0.f, 0.f};
        acc = __builtin_amdgcn_mfma_f32_16x16x32_bf16(ahi[0], b0, acc, 0, 0, 0);
        acc = __builtin_amdgcn_mfma_f32_16x16x32_bf16(alo[0], b0, acc, 0, 0, 0);
        acc = __builtin_amdgcn_mfma_f32_16x16x32_bf16(ahi[1], b1, acc, 0, 0, 0);
        acc = __builtin_amdgcn_mfma_f32_16x16x32_bf16(alo[1], b1, acc, 0, 0, 0);
        float v = -INFINITY;
#pragma unroll
        for (int r = 0; r < 4; ++r)
            if (4 * q + r < lim) v = fmaxf(v, acc[r]);   // mask garbage rows
        v = fmaxf(v, __shfl_xor(v, 16, 64));
        v = fmaxf(v, __shfl_xor(v, 32, 64));
        rm[t] = fmaxf(rm[t], v);
    }
}

__device__ __forceinline__ void load_v4(const float* __restrict__ V,
                                        unsigned si, int q, float4* v4)
{
    const float* b0 = V + (size_t)si * 64 + q * 8;
    v4[0] = ((const float4*)b0)[0];
    v4[1] = ((const float4*)b0)[1];
    const float* b1 = b0 + 32;
    v4[2] = ((const float4*)b1)[0];
    v4[3] = ((const float4*)b1)[1];
}

// Lane-parallel replica prefix: lane r<8 holds replica r's raw counter.
__device__ __forceinline__ int make_prefix(unsigned cntv, unsigned ub,
                                           int lane, bool& ov)
{
    unsigned degr = cntv - ub;
    if (lane >= 8) degr = 0;
    ov = (__ballot(degr > CAPR) != 0ULL);
    if (degr > CAPR) degr = CAPR;
    int incl = (int)degr;
    int t = __shfl_up(incl, 1, 64); if (lane >= 1) incl += t;
    t = __shfl_up(incl, 2, 64);     if (lane >= 2) incl += t;
    t = __shfl_up(incl, 4, 64);     if (lane >= 4) incl += t;
    return incl;            // lanes 0..7 valid
}

// slot g of node n's concatenated 8-replica list -> bucket element index
__device__ __forceinline__ int merge_bkt_idx(int incl, int g, int n)
{
    int rsel = 0, pbase = 0;
#pragma unroll
    for (int r = 1; r < 8; ++r) {
        int pr = __shfl(incl, r - 1, 64);     // exclusive prefix of replica r
        if (g >= pr) { rsel = r; pbase = pr; }
    }
    int slot = g - pbase;
    if (slot < 0) slot = 0;
    if (slot > CAPR - 1) slot = CAPR - 1;
    return (rsel * RNPAD + n) * CAPR + slot;
}

// Stage a node's merged bucket list into a per-wave LDS row (R10 spill fix:
// prefix/incl state dies inside this function — nothing rotates in VGPRs).
// Inactive lanes collapse to one broadcast address (g=0). Returns deg<=MCAP.
__device__ __forceinline__ int stage_row(
    unsigned cnt8, unsigned ub, int lane, int node,
    const unsigned short* __restrict__ bk,
    unsigned short* __restrict__ row, bool& ov)
{
    int incl = make_prefix(cnt8, ub, lane, ov);
    int deg = __shfl(incl, 7, 64);
    if (deg > MCAP) deg = MCAP;                // P ~ 1e-18 at Poisson(16)
    const int g = (lane < deg) ? lane : 0;
    const int idx = merge_bkt_idx(incl, g, node);
    unsigned short val = bk[idx];
    if (lane < deg) row[lane] = val;
    return deg;
}

// ---------------------------------------------------------------------------
// K3: wave per node, 3-deep pipeline; merged list staged in LDS rows
// (3 rotating 64-ushort rows per wave, 1.5 KB/block). Iter for node n:
//   (1) issue cnt(n+3s)    [lanes 0..7, 1 VGPR]
//   (2) prefix+gather(n+2s) -> ds_write row_w
//   (3) ds_read row_v slot m -> V tile-0 prefetch + U prefetch for n+1s
//   (4) compute n from prefetched vA/ufA; tiles>=1 read row_c inline
// Persistent VGPR state ~55 (vA,ufA,ufB + scalars) — fits (256,4) cap 128.
// ---------------------------------------------------------------------------
__global__ __launch_bounds__(256, 4) void node_kernel(
    const unsigned* __restrict__ uc, const unsigned short* __restrict__ bk,
    const int2* __restrict__ ovf,
    const float* __restrict__ U, const float* __restrict__ V,
    const __bf16* __restrict__ w2h, const float* __restrict__ b2,
    float* __restrict__ out)
{
    __shared__ unsigned short srows[4][3][MCAP];

    const int w    = (int)(threadIdx.x >> 6);
    const int lane = threadIdx.x & 63;
    const int m    = lane & 15;
    const int q    = lane >> 4;
    const int wave = (int)((blockIdx.x * blockDim.x + threadIdx.x) >> 6);
    const int nwav = (int)((gridDim.x * blockDim.x) >> 6);
    const int last = N_NODES - 1;

    const float b2v = b2[lane];
    const unsigned ub = uc[(size_t)NREP * RNPAD];

#define ISSUE_CNT(n) ((lane < 8) ? uc[lane * RNPAD + (n)] : 0u)
#define LOAD_UF(n, uf)                                                       \
    {  const float* ub0_ = U + (size_t)(n) * 64 + q * 8;                     \
       (uf)[0] = ((const float4*)ub0_)[0];                                   \
       (uf)[1] = ((const float4*)ub0_)[1];                                   \
       (uf)[2] = ((const float4*)(ub0_ + 32))[0];                            \
       (uf)[3] = ((const float4*)(ub0_ + 32))[1]; }

    // rotating LDS rows: rc = compute row (node n), rv = V-prefetch row
    // (node n+s), rw = stage row (node n+2s)
    unsigned short* rc = srows[w][0];
    unsigned short* rv = srows[w][1];
    unsigned short* rw = srows[w][2];

    // ---- prologue ----
    const int n0 = wave;                         // wave < 4096 < N_NODES
    int n1 = n0 + nwav;     if (n1 > last) n1 = last;
    int n2 = n0 + 2 * nwav; if (n2 > last) n2 = last;

    unsigned c0 = ISSUE_CNT(n0);
    unsigned c1 = ISSUE_CNT(n1);
    unsigned cntC = ISSUE_CNT(n2);

    bool ovA, ovB;
    int degA = stage_row(c0, ub, lane, n0, bk, rc, ovA);   // row for node n0
    int degB = stage_row(c1, ub, lane, n1, bk, rv, ovB);   // row for node n1

    float4 vA[4];
    {
        int el = m; if (el > degA - 1) el = (degA > 0) ? degA - 1 : 0;
        unsigned si = rc[el];                    // ds_read (garbage ok if deg=0)
        if (si >= N_NODES) si = N_NODES - 1;     // clamp any ushort
        load_v4(V, si, q, vA);
    }
    float4 ufA[4], ufB[4];
    LOAD_UF(n0, ufA);
    LOAD_UF(n1, ufB);

    for (int n = n0; n < N_NODES; n += nwav) {
        int nn1 = n + nwav;     if (nn1 > last) nn1 = last;
        int nn2 = n + 2 * nwav; if (nn2 > last) nn2 = last;
        int nn3 = n + 3 * nwav; if (nn3 > last) nn3 = last;

        // (1) issue cnt for node n+3s
        unsigned cntD = ISSUE_CNT(nn3);

        // (2) stage merged list for node n+2s into rw (cntC arrived)
        bool ovC;
        int degC = stage_row(cntC, ub, lane, nn2, bk, rw, ovC);

        // (3) V tile-0 + U prefetch for node n+1s from rv
        float4 vB[4];
        {
            int el = m; if (el > degB - 1) el = (degB > 0) ? degB - 1 : 0;
            unsigned si = rv[el];
            if (si >= N_NODES) si = N_NODES - 1;
            load_v4(V, si, q, vB);
        }

        // (4) compute node n from prefetched vA/ufA; tiles>=1 via rc
        const int deg = degA;
        float rm[4] = {-INFINITY, -INFINITY, -INFINITY, -INFINITY};
        const int lim0 = (deg < 16) ? deg : 16;
        tile_mfma_max(ufA, vA, w2h, m, q, lim0, rm);

        for (int base = 16; base < deg; base += 16) {
            int el = base + m; if (el > deg - 1) el = deg - 1;   // dup-pad
            unsigned si = rc[el];
            if (si >= N_NODES) si = N_NODES - 1;
            float4 v4[4];
            load_v4(V, si, q, v4);
            int lim = deg - base; if (lim > 16) lim = 16;
            tile_mfma_max(ufA, v4, w2h, m, q, lim, rm);
        }

        if (ovA) {   // exact fallback: some replica overflowed -> scan list
            unsigned nou = uc[(size_t)NREP * RNPAD + 16] - ub;
            int no = (nou < MAX_OVF) ? (int)nou : MAX_OVF;
            for (int o = 0; o < no; ++o) {
                const int2 ds = ovf[o];
                if (ds.x != n) continue;
                unsigned si = (unsigned)ds.y;
                if (si >= N_NODES) si = N_NODES - 1;
                float4 v4[4];
                load_v4(V, si, q, v4);
                tile_mfma_max(ufA, v4, w2h, m, q, 16, rm);
            }
        }

        const float sel = (q == 0) ? rm[0] : (q == 1) ? rm[1]
                        : (q == 2) ? rm[2] : rm[3];      // col == lane
        out[(size_t)n * 64 + lane] = (deg != 0) ? tanhf(sel + b2v) : 0.f;

        // (5) rotate: rows, scalars, prefetch registers; load next U
        unsigned short* tmp = rc; rc = rv; rv = rw; rw = tmp;
        degA = degB; degB = degC;
        ovA = ovB;   ovB = ovC;
        cntC = cntD;
#pragma unroll
        for (int i = 0; i < 4; ++i) { vA[i] = vB[i]; ufA[i] = ufB[i]; }
        LOAD_UF(nn2, ufB);    // next iter's B node == current nn2
    }
#undef ISSUE_CNT
#undef LOAD_UF
}

// ---------------------------------------------------------------------------
extern "C" void kernel_launch(void* const* d_in, const int* in_sizes, int n_in,
                              void* d_out, int out_size, void* d_ws, size_t ws_size,
                              hipStream_t stream)
{
    const float* x  = (const float*)d_in[0];
    const int*   ei = (const int*)d_in[1];
    const float* W1 = (const float*)d_in[2];
    const float* b1 = (const float*)d_in[3];
    const float* W2 = (const float*)d_in[4];
    const float* b2 = (const float*)d_in[5];
    float* out = (float*)d_out;

    char* p = (char*)d_ws;
    float* U = (float*)p;                  p += (size_t)N_NODES * 64 * 4;
    float* V = (float*)p;                  p += (size_t)N_NODES * 64 * 4;
    __bf16* w2h = (__bf16*)p;              p += 64 * 64 * 2;
    unsigned* uc = (unsigned*)p;           p += ((size_t)NREP * RNPAD + 32) * 4;
    int2* ovf = (int2*)p;                  p += (size_t)MAX_OVF * 8;
    unsigned short* bk = (unsigned short*)p;
    p += (size_t)NREP * RNPAD * CAPR * 2;

    prep_kernel<<<PREP_GRID, 256, 0, stream>>>(x, W1, b1, W2, U, V, w2h);
    scatter_kernel<<<2048, 256, 0, stream>>>(ei, uc, bk, ovf);
    node_kernel<<<1024, 256, 0, stream>>>(uc, bk, ovf, U, V, w2h, b2, out);
}

// Round 12
// 224.234 us; speedup vs baseline: 1.4329x; 1.0560x over previous
//
#include <hip/hip_runtime.h>
#include <hip/hip_bf16.h>
#include <math.h>

#define N_NODES 50000
#define N_EDGES 800000
#define RNPAD   50048   // per-replica counter stride (>= N_NODES, 16-aligned)
#define NREP    8       // one counter/bucket replica per XCD
#define CAPR    16      // bucket row per replica = 16 ushorts = 32B
#define MAX_OVF 8192    // exact-correctness overflow list (per-replica >CAPR)
#define MCAP    64      // merged row cap; P(Poisson(16) deg > 64) ~ 1e-18
#define OVBIT   (1 << 30)

typedef __bf16 bf16x8 __attribute__((ext_vector_type(8)));
typedef float f32x4 __attribute__((ext_vector_type(4)));

// ---------------------------------------------------------------------------
// K1: prep (R8 verbatim). [0,1024): U=(W1a-W1b)x+b1, V=W1b x (wave/node);
// [1024,1040): W2 -> bf16.
// ---------------------------------------------------------------------------
#define UV_BLOCKS 1024
#define W2_BLOCKS 16
#define PREP_GRID (UV_BLOCKS + W2_BLOCKS)

__global__ __launch_bounds__(256) void prep_kernel(
    const float* __restrict__ x, const float* __restrict__ W1,
    const float* __restrict__ b1, const float* __restrict__ W2,
    float* __restrict__ U, float* __restrict__ V, __bf16* __restrict__ w2h)
{
    const int blk = blockIdx.x;
    if (blk < UV_BLOCKS) {
        const int lane = threadIdx.x & 63;
        const int wave = (int)((blk * 256 + threadIdx.x) >> 6);
        const int nwav = UV_BLOCKS * 4;

        float wa[64], wb[64];
#pragma unroll
        for (int k4 = 0; k4 < 16; ++k4) {
            float4 pa = *(const float4*)(W1 + lane * 128 + k4 * 4);
            float4 pb = *(const float4*)(W1 + lane * 128 + 64 + k4 * 4);
            wa[k4 * 4 + 0] = pa.x - pb.x;  wb[k4 * 4 + 0] = pb.x;
            wa[k4 * 4 + 1] = pa.y - pb.y;  wb[k4 * 4 + 1] = pb.y;
            wa[k4 * 4 + 2] = pa.z - pb.z;  wb[k4 * 4 + 2] = pb.z;
            wa[k4 * 4 + 3] = pa.w - pb.w;  wb[k4 * 4 + 3] = pb.w;
        }
        const float bias = b1[lane];

        for (int i = wave; i < N_NODES; i += nwav) {
            float xv = x[i * 64 + lane];
            float u = bias, v = 0.f;
#pragma unroll
            for (int k = 0; k < 64; ++k) {
                float xk = __int_as_float(
                    __builtin_amdgcn_readlane(__float_as_int(xv), k));
                u = fmaf(wa[k], xk, u);
                v = fmaf(wb[k], xk, v);
            }
            U[i * 64 + lane] = u;
            V[i * 64 + lane] = v;
        }
    } else {
        const int i = (blk - UV_BLOCKS) * 256 + threadIdx.x;
        if (i < 64 * 64) w2h[i] = (__bf16)W2[i];
    }
}

// ---------------------------------------------------------------------------
// K2: XCD-private bucket scatter (R9 verbatim — finally measurable this
// round). Atomics/bucket writes stay in the local XCD's L2; no cross-XCD
// line migration. Correct under ANY block->XCD mapping (merge sums all 8).
// Poison-base: slot NREP*RNPAD untouched; overflow cursor at +16.
// ---------------------------------------------------------------------------
__global__ __launch_bounds__(256) void scatter_kernel(
    const int* __restrict__ ei, unsigned* __restrict__ uc,
    unsigned short* __restrict__ bk, int2* __restrict__ ovf)
{
    unsigned xcc = 0;
    asm volatile("s_getreg_b32 %0, hwreg(HW_REG_XCC_ID)" : "=s"(xcc));
    const int rep = (int)(xcc & 7u);
    unsigned* __restrict__ myc = uc + (size_t)rep * RNPAD;
    unsigned short* __restrict__ myb = bk + (size_t)rep * RNPAD * CAPR;
    const unsigned ub = uc[(size_t)NREP * RNPAD];

    const int tid = blockIdx.x * 256 + threadIdx.x;
    const int stride = gridDim.x * 256;
    for (int e = tid; e < N_EDGES; e += stride) {
        const int s = ei[e];
        const int d = ei[N_EDGES + e];
        unsigned pos = atomicAdd(&myc[d], 1u) - ub;
        if (pos < CAPR) {
            myb[d * CAPR + (int)pos] = (unsigned short)s;
        } else {
            unsigned o = atomicAdd(&uc[(size_t)NREP * RNPAD + 16], 1u) - ub;
            if (o < MAX_OVF) ovf[o] = make_int2(d, s);
        }
    }
}

// Lane-parallel replica prefix: lane r<8 holds replica r's raw counter.
__device__ __forceinline__ int make_prefix(unsigned cntv, unsigned ub,
                                           int lane, bool& ov)
{
    unsigned degr = cntv - ub;
    if (lane >= 8) degr = 0;
    ov = (__ballot(degr > CAPR) != 0ULL);
    if (degr > CAPR) degr = CAPR;
    int incl = (int)degr;
    int t = __shfl_up(incl, 1, 64); if (lane >= 1) incl += t;
    t = __shfl_up(incl, 2, 64);     if (lane >= 2) incl += t;
    t = __shfl_up(incl, 4, 64);     if (lane >= 4) incl += t;
    return incl;            // lanes 0..7 valid
}

// slot g of node n's concatenated 8-replica list -> bucket element index
__device__ __forceinline__ int merge_bkt_idx(int incl, int g, int n)
{
    int rsel = 0, pbase = 0;
#pragma unroll
    for (int r = 1; r < 8; ++r) {
        int pr = __shfl(incl, r - 1, 64);     // exclusive prefix of replica r
        if (g >= pr) { rsel = r; pbase = pr; }
    }
    int slot = g - pbase;
    if (slot < 0) slot = 0;
    if (slot > CAPR - 1) slot = CAPR - 1;
    return (rsel * RNPAD + n) * CAPR + slot;
}

// ---------------------------------------------------------------------------
// K2b: replica merge — R10/R11's spill source moved into its own 4-VGPR-class
// kernel. Wave per node: lanes 0..7 read replica counters, transient shfl
// prefix, all lanes gather their merged slot, ONE coalesced 128B row write +
// packed count (deg | OVBIT). mcnt[N_NODES] = resolved overflow-list length.
// ---------------------------------------------------------------------------
__global__ __launch_bounds__(256, 8) void merge_kernel(
    const unsigned* __restrict__ uc, const unsigned short* __restrict__ bk,
    int* __restrict__ mcnt, unsigned short* __restrict__ mb)
{
    const int lane = threadIdx.x & 63;
    const int wave = (int)((blockIdx.x * blockDim.x + threadIdx.x) >> 6);
    const int nwav = (int)((gridDim.x * blockDim.x) >> 6);
    const unsigned ub = uc[(size_t)NREP * RNPAD];

    if (wave == 0 && lane == 0) {
        unsigned no = uc[(size_t)NREP * RNPAD + 16] - ub;
        mcnt[N_NODES] = (no < MAX_OVF) ? (int)no : MAX_OVF;
    }

    for (int n = wave; n < N_NODES; n += nwav) {
        const unsigned cnt8 = (lane < 8) ? uc[lane * RNPAD + n] : 0u;
        bool ov;
        int incl = make_prefix(cnt8, ub, lane, ov);
        int deg = __shfl(incl, 7, 64);
        if (deg > MCAP) deg = MCAP;               // P ~ 1e-18 at Poisson(16)
        const int g = (lane < deg) ? lane : 0;    // inactive lanes broadcast
        const unsigned short val = bk[merge_bkt_idx(incl, g, n)];
        if (lane < deg) mb[(size_t)n * MCAP + lane] = val;
        if (lane == 0)  mcnt[n] = deg | (ov ? OVBIT : 0);
    }
}

// ---------------------------------------------------------------------------
// Tile compute (unchanged): repack h=leaky(uf+v) -> A hi/lo bf16; 4 MFMA per
// t (B single bf16, per-tile L1 loads); masked max, shfl-reduce over q.
// ---------------------------------------------------------------------------
__device__ __forceinline__ void tile_mfma_max(
    const float4* __restrict__ uf4, const float4* __restrict__ v4,
    const __bf16* __restrict__ w2h, int m, int q, int lim,
    float* __restrict__ rm)
{
    bf16x8 ahi[2], alo[2];
#pragma unroll
    for (int s = 0; s < 2; ++s) {
        const float4 a = uf4[2 * s], b = uf4[2 * s + 1];
        const float4 c = v4[2 * s],  d = v4[2 * s + 1];
        float hv[8] = {a.x + c.x, a.y + c.y, a.z + c.z, a.w + c.w,
                       b.x + d.x, b.y + d.y, b.z + d.z, b.w + d.w};
#pragma unroll
        for (int j = 0; j < 8; ++j) {
            float h = fmaxf(hv[j], 0.01f * hv[j]);   // LeakyReLU
            __bf16 hb = (__bf16)h;
            ahi[s][j] = hb;
            alo[s][j] = (__bf16)(h - (float)hb);     // residual
        }
    }
#pragma unroll
    for (int t = 0; t < 4; ++t) {
        const bf16x8 b0 = *(const bf16x8*)(w2h + (t * 16 + m) * 64 + q * 8);
        const bf16x8 b1 = *(const bf16x8*)(w2h + (t * 16 + m) * 64 + 32 + q * 8);
        f32x4 acc = {0.f, 0.f, 0.f, 0.f};
        acc = __builtin_amdgcn_mfma_f32_16x16x32_bf16(ahi[0], b0, acc, 0, 0, 0);
        acc = __builtin_amdgcn_mfma_f32_16x16x32_bf16(alo[0], b0, acc, 0, 0, 0);
        acc = __builtin_amdgcn_mfma_f32_16x16x32_bf16(ahi[1], b1, acc, 0, 0, 0);
        acc = __builtin_amdgcn_mfma_f32_16x16x32_bf16(alo[1], b1, acc, 0, 0, 0);
        float v = -INFINITY;
#pragma unroll
        for (int r = 0; r < 4; ++r)
            if (4 * q + r < lim) v = fmaxf(v, acc[r]);   // mask garbage rows
        v = fmaxf(v, __shfl_xor(v, 16, 64));
        v = fmaxf(v, __shfl_xor(v, 32, 64));
        rm[t] = fmaxf(rm[t], v);
    }
}

__device__ __forceinline__ void load_v4(const float* __restrict__ V,
                                        unsigned si, int q, float4* v4)
{
    const float* b0 = V + (size_t)si * 64 + q * 8;
    v4[0] = ((const float4*)b0)[0];
    v4[1] = ((const float4*)b0)[1];
    const float* b1 = b0 + 32;
    v4[2] = ((const float4*)b1)[0];
    v4[3] = ((const float4*)b1)[1];
}

// ---------------------------------------------------------------------------
// K3: node kernel — R8's proven spill-free structure verbatim (2-deep
// pipeline: cnt/bkt(n+2s), V/U(n+1s), compute n), addressing swapped to the
// merged row (mb, 64 ushorts/node) + plain packed counts (mcnt). All loads
// poison-safe (si clamp; deg=0 row is unwritten garbage -> masked by lim0=0).
// 1024 blocks @ (256,4): all resident.
// ---------------------------------------------------------------------------
__global__ __launch_bounds__(256, 4) void node_kernel(
    const int* __restrict__ mcnt, const unsigned short* __restrict__ mb,
    const int2* __restrict__ ovf,
    const float* __restrict__ U, const float* __restrict__ V,
    const __bf16* __restrict__ w2h, const float* __restrict__ b2,
    float* __restrict__ out)
{
    const int lane = threadIdx.x & 63;
    const int m    = lane & 15;
    const int q    = lane >> 4;
    const int wave = (int)((blockIdx.x * blockDim.x + threadIdx.x) >> 6);
    const int nwav = (int)((gridDim.x * blockDim.x) >> 6);
    const int last = N_NODES - 1;

    const float b2v = b2[lane];

#define LOAD_UF(n, uf)                                                       \
    {  const float* ub0_ = U + (size_t)(n) * 64 + q * 8;                     \
       (uf)[0] = ((const float4*)ub0_)[0];                                   \
       (uf)[1] = ((const float4*)ub0_)[1];                                   \
       (uf)[2] = ((const float4*)(ub0_ + 32))[0];                            \
       (uf)[3] = ((const float4*)(ub0_ + 32))[1]; }

    // ---- prologue: arm node A fully; arm cnt/bkt for node B ----
    const int nA0 = wave;                        // wave < 4096 < N_NODES
    int pB = nA0 + nwav; if (pB > last) pB = last;

    int cntA = mcnt[nA0];
    int bktA = mb[(size_t)nA0 * MCAP + m];
    float4 ufA[4];
    LOAD_UF(nA0, ufA);
    int cntB = mcnt[pB];
    int bktB = mb[(size_t)pB * MCAP + m];

    float4 vA[4];
    {
        unsigned si = (unsigned)bktA;
        if (si >= N_NODES) si = N_NODES - 1;     // poison-safe clamp
        load_v4(V, si, q, vA);
    }
    float4 ufB[4];
    LOAD_UF(pB, ufB);

    for (int n = nA0; n < N_NODES; n += nwav) {
        int pC = n + 2 * nwav; if (pC > last) pC = last;

        // (1) issue V for node B (bktB arrived during previous compute)
        unsigned siB = (unsigned)bktB;
        if (siB >= N_NODES) siB = N_NODES - 1;
        float4 vB[4];
        load_v4(V, siB, q, vB);

        // (2) issue cnt/bkt for node C
        int cntC = mcnt[pC];
        int bktC = mb[(size_t)pC * MCAP + m];

        // (3) compute node A = n
        const int deg = cntA & 0xFFFF;
        float rm[4] = {-INFINITY, -INFINITY, -INFINITY, -INFINITY};
        const int lim0 = (deg < 16) ? deg : 16;
        tile_mfma_max(ufA, vA, w2h, m, q, lim0, rm);     // tile 0 (pre-armed)

        for (int base = 16; base < deg; base += 16) {    // tiles 1..3
            int el = base + m; if (el > deg - 1) el = deg - 1;   // dup-pad
            unsigned si = (unsigned)mb[(size_t)n * MCAP + el];
            if (si >= N_NODES) si = N_NODES - 1;
            float4 v4[4];
            load_v4(V, si, q, v4);
            int lim = deg - base; if (lim > 16) lim = 16;
            tile_mfma_max(ufA, v4, w2h, m, q, lim, rm);
        }

        if (cntA & OVBIT) {   // exact fallback: replica overflowed -> scan list
            int no = mcnt[N_NODES];
            for (int o = 0; o < no; ++o) {
                const int2 ds = ovf[o];
                if (ds.x != n) continue;
                unsigned si = (unsigned)ds.y;
                if (si >= N_NODES) si = N_NODES - 1;
                float4 v4[4];
                load_v4(V, si, q, v4);
                tile_mfma_max(ufA, v4, w2h, m, q, 16, rm);
            }
        }

        const float sel = (q == 0) ? rm[0] : (q == 1) ? rm[1]
                        : (q == 2) ? rm[2] : rm[3];      // col == lane
        out[(size_t)n * 64 + lane] = (deg != 0) ? tanhf(sel + b2v) : 0.f;

        // (4) rotate pipeline state; issue U for next B (== pC)
        cntA = cntB; cntB = cntC;
        bktB = bktC;
#pragma unroll
        for (int i = 0; i < 4; ++i) { vA[i] = vB[i]; ufA[i] = ufB[i]; }
        LOAD_UF(pC, ufB);
    }
#undef LOAD_UF
}

// ---------------------------------------------------------------------------
extern "C" void kernel_launch(void* const* d_in, const int* in_sizes, int n_in,
                              void* d_out, int out_size, void* d_ws, size_t ws_size,
                              hipStream_t stream)
{
    const float* x  = (const float*)d_in[0];
    const int*   ei = (const int*)d_in[1];
    const float* W1 = (const float*)d_in[2];
    const float* b1 = (const float*)d_in[3];
    const float* W2 = (const float*)d_in[4];
    const float* b2 = (const float*)d_in[5];
    float* out = (float*)d_out;

    char* p = (char*)d_ws;
    float* U = (float*)p;                  p += (size_t)N_NODES * 64 * 4;
    float* V = (float*)p;                  p += (size_t)N_NODES * 64 * 4;
    __bf16* w2h = (__bf16*)p;              p += 64 * 64 * 2;
    unsigned* uc = (unsigned*)p;           p += ((size_t)NREP * RNPAD + 32) * 4;
    int2* ovf = (int2*)p;                  p += (size_t)MAX_OVF * 8;
    unsigned short* bk = (unsigned short*)p;
    p += (size_t)NREP * RNPAD * CAPR * 2;
    int* mcnt = (int*)p;                   p += (size_t)(N_NODES + 16) * 4;
    unsigned short* mb = (unsigned short*)p;
    p += (size_t)N_NODES * MCAP * 2;

    prep_kernel<<<PREP_GRID, 256, 0, stream>>>(x, W1, b1, W2, U, V, w2h);
    scatter_kernel<<<2048, 256, 0, stream>>>(ei, uc, bk, ovf);
    merge_kernel<<<512, 256, 0, stream>>>(uc, bk, mcnt, mb);
    node_kernel<<<1024, 256, 0, stream>>>(mcnt, mb, ovf, U, V, w2h, b2, out);
}

// Round 13
// 215.117 us; speedup vs baseline: 1.4936x; 1.0424x over previous
//
#include <hip/hip_runtime.h>
#include <hip/hip_bf16.h>
#include <math.h>

#define N_NODES 50000
#define N_EDGES 800000
#define ROWU    16      // row = 16 uints = 64B: [cnt | 30 ushort slots]
#define CAPN    30      // in-row slots; P(Poisson(16) deg > 30) ~ 2e-4
#define MAX_OVF 8192    // exact-correctness overflow list
#define OVROW   ((size_t)(N_NODES + 1) * ROWU)   // overflow cursor cell
#define UBROW   ((size_t)N_NODES * ROWU)         // untouched poison-base cell

typedef __bf16 bf16x8 __attribute__((ext_vector_type(8)));
typedef float f32x4 __attribute__((ext_vector_type(4)));

// ---------------------------------------------------------------------------
// K1: prep (R8 verbatim). [0,1024): U=(W1a-W1b)x+b1, V=W1b x (wave/node);
// [1024,1040): W2 -> bf16 (single-precision B; A stays hi/lo split).
// ---------------------------------------------------------------------------
#define UV_BLOCKS 1024
#define W2_BLOCKS 16
#define PREP_GRID (UV_BLOCKS + W2_BLOCKS)

__global__ __launch_bounds__(256) void prep_kernel(
    const float* __restrict__ x, const float* __restrict__ W1,
    const float* __restrict__ b1, const float* __restrict__ W2,
    float* __restrict__ U, float* __restrict__ V, __bf16* __restrict__ w2h)
{
    const int blk = blockIdx.x;
    if (blk < UV_BLOCKS) {
        const int lane = threadIdx.x & 63;
        const int wave = (int)((blk * 256 + threadIdx.x) >> 6);
        const int nwav = UV_BLOCKS * 4;

        float wa[64], wb[64];
#pragma unroll
        for (int k4 = 0; k4 < 16; ++k4) {
            float4 pa = *(const float4*)(W1 + lane * 128 + k4 * 4);
            float4 pb = *(const float4*)(W1 + lane * 128 + 64 + k4 * 4);
            wa[k4 * 4 + 0] = pa.x - pb.x;  wb[k4 * 4 + 0] = pb.x;
            wa[k4 * 4 + 1] = pa.y - pb.y;  wb[k4 * 4 + 1] = pb.y;
            wa[k4 * 4 + 2] = pa.z - pb.z;  wb[k4 * 4 + 2] = pb.z;
            wa[k4 * 4 + 3] = pa.w - pb.w;  wb[k4 * 4 + 3] = pb.w;
        }
        const float bias = b1[lane];

        for (int i = wave; i < N_NODES; i += nwav) {
            float xv = x[i * 64 + lane];
            float u = bias, v = 0.f;
#pragma unroll
            for (int k = 0; k < 64; ++k) {
                float xk = __int_as_float(
                    __builtin_amdgcn_readlane(__float_as_int(xv), k));
                u = fmaf(wa[k], xk, u);
                v = fmaf(wb[k], xk, v);
            }
            U[i * 64 + lane] = u;
            V[i * 64 + lane] = v;
        }
    } else {
        const int i = (blk - UV_BLOCKS) * 256 + threadIdx.x;
        if (i < 64 * 64) w2h[i] = (__bf16)W2[i];
    }
}

// ---------------------------------------------------------------------------
// K2: single-copy scatter, counter+slots fused into ONE 64B line per node.
// R12 lesson: XCD-replicas bought nothing (device atomics execute memory-
// side); the measurable currency is line-ops. Fusing cnt+bucket into one
// line halves scatter's line-ops (atomic acquires the line, the dependent
// store hits the same line) and gives the node kernel cnt+tile0 slots in a
// single fetch. Poison-base: UBROW untouched; deg = cnt - ub. Slots hold
// poison beyond deg -> node's si-clamp + lim-mask absorb them.
// ---------------------------------------------------------------------------
__global__ __launch_bounds__(256) void scatter_kernel(
    const int* __restrict__ ei, unsigned* __restrict__ rows,
    int2* __restrict__ ovf)
{
    int e = blockIdx.x * 256 + threadIdx.x;
    if (e >= N_EDGES) return;
    const unsigned ub = rows[UBROW];
    const int s = ei[e];
    const int d = ei[N_EDGES + e];
    unsigned pos = atomicAdd(&rows[(size_t)d * ROWU], 1u) - ub;
    if (pos < CAPN) {
        ((unsigned short*)(rows + (size_t)d * ROWU + 1))[pos] = (unsigned short)s;
    } else {
        unsigned o = atomicAdd(&rows[OVROW], 1u) - ub;
        if (o < MAX_OVF) ovf[o] = make_int2(d, s);
    }
}

// ---------------------------------------------------------------------------
// Tile compute (unchanged numerics, absmax 0.0078): h=leaky(uf+v) -> A hi/lo
// bf16; 4 MFMA per t (B single bf16, per-tile L1 loads); masked max,
// shfl-reduce over q.
//   A: lane m+16q holds A[m][k], k=32s+8q+j   B: lane n+16q holds W2[n][k]
//   D: lane holds D[4q+r][lane&15]
// ---------------------------------------------------------------------------
__device__ __forceinline__ void tile_mfma_max(
    const float4* __restrict__ uf4, const float4* __restrict__ v4,
    const __bf16* __restrict__ w2h, int m, int q, int lim,
    float* __restrict__ rm)
{
    bf16x8 ahi[2], alo[2];
#pragma unroll
    for (int s = 0; s < 2; ++s) {
        const float4 a = uf4[2 * s], b = uf4[2 * s + 1];
        const float4 c = v4[2 * s],  d = v4[2 * s + 1];
        float hv[8] = {a.x + c.x, a.y + c.y, a.z + c.z, a.w + c.w,
                       b.x + d.x, b.y + d.y, b.z + d.z, b.w + d.w};
#pragma unroll
        for (int j = 0; j < 8; ++j) {
            float h = fmaxf(hv[j], 0.01f * hv[j]);   // LeakyReLU
            __bf16 hb = (__bf16)h;
            ahi[s][j] = hb;
            alo[s][j] = (__bf16)(h - (float)hb);     // residual
        }
    }
#pragma unroll
    for (int t = 0; t < 4; ++t) {
        const bf16x8 b0 = *(const bf16x8*)(w2h + (t * 16 + m) * 64 + q * 8);
        const bf16x8 b1 = *(const bf16x8*)(w2h + (t * 16 + m) * 64 + 32 + q * 8);
        f32x4 acc = {0.f, 0.f, 0.f, 0.f};
        acc = __builtin_amdgcn_mfma_f32_16x16x32_bf16(ahi[0], b0, acc, 0, 0, 0);
        acc = __builtin_amdgcn_mfma_f32_16x16x32_bf16(alo[0], b0, acc, 0, 0, 0);
        acc = __builtin_amdgcn_mfma_f32_16x16x32_bf16(ahi[1], b1, acc, 0, 0, 0);
        acc = __builtin_amdgcn_mfma_f32_16x16x32_bf16(alo[1], b1, acc, 0, 0, 0);
        float v = -INFINITY;
#pragma unroll
        for (int r = 0; r < 4; ++r)
            if (4 * q + r < lim) v = fmaxf(v, acc[r]);   // mask garbage rows
        v = fmaxf(v, __shfl_xor(v, 16, 64));
        v = fmaxf(v, __shfl_xor(v, 32, 64));
        rm[t] = fmaxf(rm[t], v);
    }
}

__device__ __forceinline__ void load_v4(const float* __restrict__ V,
                                        unsigned si, int q, float4* v4)
{
    const float* b0 = V + (size_t)si * 64 + q * 8;
    v4[0] = ((const float4*)b0)[0];
    v4[1] = ((const float4*)b0)[1];
    const float* b1 = b0 + 32;
    v4[2] = ((const float4*)b1)[0];
    v4[3] = ((const float4*)b1)[1];
}

// ---------------------------------------------------------------------------
// K3: node kernel — R8/R12's proven spill-free 2-deep pipeline, addressing
// swapped to the fused rows (cnt + slots share one line; bucket read is
// count-independent since garbage slots are clamp+mask-safe). Grid 2048 @
// VGPR<=64 -> 8 blocks/CU resident (R12 ran 4/CU; doubling TLP hides the
// V-gather latency that kept VALUBusy at 42%).
// ---------------------------------------------------------------------------
__global__ __launch_bounds__(256, 4) void node_kernel(
    const unsigned* __restrict__ rows, const int2* __restrict__ ovf,
    const float* __restrict__ U, const float* __restrict__ V,
    const __bf16* __restrict__ w2h, const float* __restrict__ b2,
    float* __restrict__ out)
{
    const int lane = threadIdx.x & 63;
    const int m    = lane & 15;
    const int q    = lane >> 4;
    const int wave = (int)((blockIdx.x * blockDim.x + threadIdx.x) >> 6);
    const int nwav = (int)((gridDim.x * blockDim.x) >> 6);
    const int last = N_NODES - 1;

    const float b2v = b2[lane];
    const unsigned ub = rows[UBROW];

#define LOAD_UF(n, uf)                                                       \
    {  const float* ub0_ = U + (size_t)(n) * 64 + q * 8;                     \
       (uf)[0] = ((const float4*)ub0_)[0];                                   \
       (uf)[1] = ((const float4*)ub0_)[1];                                   \
       (uf)[2] = ((const float4*)(ub0_ + 32))[0];                            \
       (uf)[3] = ((const float4*)(ub0_ + 32))[1]; }
#define SLOT(n, el) ((const unsigned short*)(rows + (size_t)(n) * ROWU + 1))[el]

    // ---- prologue: arm node A fully; arm cnt/bkt for node B ----
    const int nA0 = wave;                        // wave < 8192 < N_NODES
    int pB = nA0 + nwav; if (pB > last) pB = last;

    unsigned cntA = rows[(size_t)nA0 * ROWU];
    int      bktA = SLOT(nA0, m);                // count-independent (m < 30)
    float4 ufA[4];
    LOAD_UF(nA0, ufA);
    unsigned cntB = rows[(size_t)pB * ROWU];
    int      bktB = SLOT(pB, m);

    float4 vA[4];
    {
        unsigned si = (unsigned)bktA;
        if (si >= N_NODES) si = N_NODES - 1;     // poison-safe clamp
        load_v4(V, si, q, vA);
    }
    float4 ufB[4];
    LOAD_UF(pB, ufB);

    for (int n = nA0; n < N_NODES; n += nwav) {
        int pC = n + 2 * nwav; if (pC > last) pC = last;

        // (1) issue V for node B (bktB arrived during previous compute)
        unsigned siB = (unsigned)bktB;
        if (siB >= N_NODES) siB = N_NODES - 1;
        float4 vB[4];
        load_v4(V, siB, q, vB);

        // (2) issue cnt/bkt for node C (same line)
        unsigned cntC = rows[(size_t)pC * ROWU];
        int      bktC = SLOT(pC, m);

        // (3) compute node A = n
        const unsigned c = cntA - ub;
        const int deg = (c < CAPN) ? (int)c : CAPN;
        float rm[4] = {-INFINITY, -INFINITY, -INFINITY, -INFINITY};
        const int lim0 = (deg < 16) ? deg : 16;
        tile_mfma_max(ufA, vA, w2h, m, q, lim0, rm);     // tile 0 (pre-armed)

        if (deg > 16) {                                  // tile 1 (slots 16..29)
            int el = 16 + m; if (el > deg - 1) el = deg - 1;   // dup-pad, <=29
            unsigned si = (unsigned)SLOT(n, el);
            if (si >= N_NODES) si = N_NODES - 1;
            float4 v4[4];
            load_v4(V, si, q, v4);
            tile_mfma_max(ufA, v4, w2h, m, q, deg - 16, rm);
        }

        if (c > CAPN) {   // exact fallback: row overflowed -> scan list
            unsigned nou = rows[OVROW] - ub;
            int no = (nou < MAX_OVF) ? (int)nou : MAX_OVF;
            for (int o = 0; o < no; ++o) {
                const int2 ds = ovf[o];
                if (ds.x != n) continue;
                unsigned si = (unsigned)ds.y;
                if (si >= N_NODES) si = N_NODES - 1;
                float4 v4[4];
                load_v4(V, si, q, v4);
                tile_mfma_max(ufA, v4, w2h, m, q, 16, rm);
            }
        }

        const float sel = (q == 0) ? rm[0] : (q == 1) ? rm[1]
                        : (q == 2) ? rm[2] : rm[3];      // col == lane
        out[(size_t)n * 64 + lane] = (c != 0u) ? tanhf(sel + b2v) : 0.f;

        // (4) rotate pipeline state; issue U for next B (== pC)
        cntA = cntB; cntB = cntC;
        bktB = bktC;
#pragma unroll
        for (int i = 0; i < 4; ++i) { vA[i] = vB[i]; ufA[i] = ufB[i]; }
        LOAD_UF(pC, ufB);
    }
#undef LOAD_UF
#undef SLOT
}

// ---------------------------------------------------------------------------
extern "C" void kernel_launch(void* const* d_in, const int* in_sizes, int n_in,
                              void* d_out, int out_size, void* d_ws, size_t ws_size,
                              hipStream_t stream)
{
    const float* x  = (const float*)d_in[0];
    const int*   ei = (const int*)d_in[1];
    const float* W1 = (const float*)d_in[2];
    const float* b1 = (const float*)d_in[3];
    const float* W2 = (const float*)d_in[4];
    const float* b2 = (const float*)d_in[5];
    float* out = (float*)d_out;

    char* p = (char*)d_ws;
    float* U = (float*)p;                  p += (size_t)N_NODES * 64 * 4;
    float* V = (float*)p;                  p += (size_t)N_NODES * 64 * 4;
    __bf16* w2h = (__bf16*)p;              p += 64 * 64 * 2;
    unsigned* rows = (unsigned*)p;         p += (size_t)(N_NODES + 2) * ROWU * 4;
    int2* ovf = (int2*)p;                  p += (size_t)MAX_OVF * 8;

    prep_kernel<<<PREP_GRID, 256, 0, stream>>>(x, W1, b1, W2, U, V, w2h);
    scatter_kernel<<<(N_EDGES + 255) / 256, 256, 0, stream>>>(ei, rows, ovf);
    node_kernel<<<2048, 256, 0, stream>>>(rows, ovf, U, V, w2h, b2, out);
}